// Round 10
// baseline (128.612 us; speedup 1.0000x reference)
//
#include <hip/hip_runtime.h>
#include <cstdint>

// Chamfer distance, B=8, N=M=4096, D=128, f32 in, scalar f32 out.
// R10: 2 blocks/CU via small LDS. R9 proved 75KB blocks never pair (effective
// LDS pool < 151KB). Now y-tile = 64 cols (16KB, dbuf) -> ~38KB/block, so two
// 512-thr blocks (8 waves, 128 VGPR) co-reside: 4 waves/SIMD, cross-block
// overlap of DMA drain vs MFMA. Same total staged volume (64MB), same 1:4
// ds_read:MFMA ratio.
// Workspace: xb(8M) yb(8M) x2(128K) y2(128K) rowpart(1M) colpart(1M) partial.

#define B_   8
#define N_   4096
#define M_   4096
#define D_   128
#define TPB  8               // y-tiles (64 cols) per block -> 512 cols/chunk
#define ROWS_PB 512          // x-rows per block = 8 waves * 64
#define XG   (N_ / ROWS_PB)  // 8 x-groups
#define CHUNKS (M_ / (TPB * 64))   // 8 y-chunks

typedef __bf16 bf16x8 __attribute__((ext_vector_type(8)));
typedef float  f32x4  __attribute__((ext_vector_type(4)));
typedef unsigned int u32;

static __device__ __forceinline__ unsigned short f2bf(float f) {
  unsigned u = __float_as_uint(f);
  u += 0x7FFFu + ((u >> 16) & 1u);   // round-to-nearest-even
  return (unsigned short)(u >> 16);
}

static __device__ __forceinline__ void gld16(void* lds, const void* g) {
  __builtin_amdgcn_global_load_lds(
      (const __attribute__((address_space(1))) void*)g,
      (__attribute__((address_space(3))) void*)lds, 16, 0, 0);
}

// Pass 1: wave handles 2 rows (32 lanes x float4 each). xb = bf16(-2x),
// yb = bf16(y), fp32 norms.
__global__ __launch_bounds__(256) void pass1_prep(
    const float* __restrict__ x, const float* __restrict__ y,
    unsigned short* __restrict__ xb, unsigned short* __restrict__ yb,
    float* __restrict__ x2, float* __restrict__ y2)
{
  const int ROWS = B_ * N_;
  int gw   = (blockIdx.x * 256 + threadIdx.x) >> 6;   // wave id
  int lane = threadIdx.x & 63;
  int half = lane >> 5, sub = lane & 31;
  int row2 = gw * 2 + half;                  // 0 .. 2*ROWS-1 (x rows then y rows)
  bool isx = row2 < ROWS;
  const float* src; unsigned short* dst; float* nrm; int row;
  if (isx) { src = x; dst = xb; nrm = x2; row = row2; }
  else     { src = y; dst = yb; nrm = y2; row = row2 - ROWS; }
  size_t base = (size_t)row * D_ + sub * 4;
  float4 v = *(const float4*)(src + base);
  float sx = isx ? -2.0f : 1.0f;
  u32 p0 = (u32)f2bf(sx * v.x) | ((u32)f2bf(sx * v.y) << 16);
  u32 p1 = (u32)f2bf(sx * v.z) | ((u32)f2bf(sx * v.w) << 16);
  *(uint2*)(dst + base) = make_uint2(p0, p1);
  float s = v.x * v.x + v.y * v.y + v.z * v.z + v.w * v.w;
  #pragma unroll
  for (int m = 1; m < 32; m <<= 1) s += __shfl_xor(s, m, 64);
  if (sub == 0) nrm[row] = s;
}

// Pass 2: block = 512 x-rows (8 waves x 64 rows = 4 row-tiles of 16), loops
// over TPB y-tiles of 64 cols. y staged by global_load_lds into XOR-swizzled
// LDS (row r, logical 16B-chunk c at physical chunk c^(r&15); 256 B rows).
// Fragment layouts (HW-verified):
//   A/B operand: lane holds elems [row=lane&15][k=(lane>>4)*8 + 0..7]
//   C/D:         lane reg r holds [row=(lane>>4)*4+r][col=lane&15]
// acc = -2<x,y>; epilogue s = acc + x2_i + y2_j = d^2; mins on d^2.
__global__
__launch_bounds__(512)
__attribute__((amdgpu_waves_per_eu(2)))   // proven combo: allocator lands at 128 VGPRs
void pass2_tile(
    const unsigned short* __restrict__ xb, const unsigned short* __restrict__ yb,
    const float* __restrict__ x2, const float* __restrict__ y2,
    float* __restrict__ rowpart, float* __restrict__ colpart)
{
  __shared__ unsigned short ys[2 * 8192];    // two 16 KB swizzled y-tiles (64 rows)
  __shared__ float cminW[2][8 * 64];         // double-buffered per-wave col mins
  __shared__ float y2s[TPB * 64];            // whole chunk's y^2 (2 KB)

  const int tid  = threadIdx.x;
  const int wave = tid >> 6;                 // 0..7
  const int lane = tid & 63;
  const int quad = lane >> 4;
  const int l15  = lane & 15;

  const int id    = blockIdx.x;        // 0..511
  const int b     = id & 7;
  const int j     = id >> 3;           // 0..63
  const int xg    = j & 7;
  const int chunk = j >> 3;            // 0..7
  const int n0    = xg * ROWS_PB;
  const int mc0   = chunk * (TPB * 64);

  // DMA: 16KB tile, 2 gld16 per lane: instr i covers bytes (wave*2+i)*1024+lane*16.
  int srcoff[2], ldsoff[2];
  #pragma unroll
  for (int i = 0; i < 2; ++i) {
    int p  = (wave * 2 + i) * 1024 + lane * 16;
    int r  = p >> 8;                 // y row 0..63
    int pc = (p >> 4) & 15;          // physical chunk
    int c  = pc ^ (r & 15);          // logical chunk
    srcoff[i] = r * D_ + c * 8;      // elements
    ldsoff[i] = (wave * 2 + i) * 1024;
  }

  // preload tile 0 + whole-chunk y2 into LDS
  {
    const unsigned short* src = yb + ((size_t)b * M_ + mc0) * D_;
    gld16((char*)ys + ldsoff[0], src + srcoff[0]);
    gld16((char*)ys + ldsoff[1], src + srcoff[1]);
  }
  if (tid < TPB * 64) y2s[tid] = y2[(size_t)b * M_ + mc0 + tid];

  // A fragments: direct global->register, rows n0 + wave*64 + rt*16 + l15.
  bf16x8 afrag[4][4];   // [kb][rt]
  const size_t xrow0 = (size_t)b * N_ + n0 + wave * 64;
  #pragma unroll
  for (int kb = 0; kb < 4; ++kb)
    #pragma unroll
    for (int rt = 0; rt < 4; ++rt)
      afrag[kb][rt] = *(const bf16x8*)(xb + (xrow0 + rt * 16 + l15) * D_ + kb * 32 + quad * 8);

  // x2 for this wave's 16 output rows (t-invariant)
  float xv[4][4];
  #pragma unroll
  for (int rt = 0; rt < 4; ++rt)
    #pragma unroll
    for (int r = 0; r < 4; ++r)
      xv[rt][r] = x2[(size_t)b * N_ + n0 + wave * 64 + rt * 16 + quad * 4 + r];

  const float FINF = __uint_as_float(0x7F800000u);
  float rmin2[4][4];
  #pragma unroll
  for (int rt = 0; rt < 4; ++rt)
    #pragma unroll
    for (int r = 0; r < 4; ++r) rmin2[rt][r] = FINF;

  #pragma unroll 1
  for (int t = 0; t < TPB; ++t) {
    const int m0 = mc0 + t * 64;
    const int d  = (t & 1) * 16384;    // current buffer byte offset
    __syncthreads();  // drains DMA for buf d (prefetch had a full iteration);
                      // fences prior buf reads and cminW[(t-1)&1] writes

    if (t + 1 < TPB) {  // prefetch next tile into the other buffer
      const unsigned short* src = yb + ((size_t)b * M_ + m0 + 64) * D_;
      char* dst = (char*)ys + (16384 - d);
      gld16(dst + ldsoff[0], src + srcoff[0]);
      gld16(dst + ldsoff[1], src + srcoff[1]);
    }

    // Flush previous tile's column mins (other cminW buffer -> no race).
    if (t > 0 && tid < 64) {
      float v = cminW[(t - 1) & 1][tid];
      #pragma unroll
      for (int w = 1; w < 8; ++w) v = fminf(v, cminW[(t - 1) & 1][w * 64 + tid]);
      colpart[(size_t)xg * (B_ * M_) + (size_t)b * M_ + (m0 - 64) + tid] = v;
    }

    #pragma unroll
    for (int ct = 0; ct < 4; ++ct) {
      f32x4 a[4];
      #pragma unroll
      for (int rt = 0; rt < 4; ++rt) a[rt] = (f32x4)(0.0f);
      #pragma unroll
      for (int kb = 0; kb < 4; ++kb) {
        const int row = ct * 16 + l15;
        const int pcB = (kb * 4 + quad) ^ l15;   // swizzled chunk
        bf16x8 bfr = *(const bf16x8*)((const char*)ys + d + row * 256 + pcB * 16);
        #pragma unroll
        for (int rt = 0; rt < 4; ++rt)
          a[rt] = __builtin_amdgcn_mfma_f32_16x16x32_bf16(afrag[kb][rt], bfr, a[rt], 0, 0, 0);
      }
      float yv = y2s[t * 64 + ct * 16 + l15];  // quads share addr -> broadcast
      float cm = FINF;
      #pragma unroll
      for (int rt = 0; rt < 4; ++rt) {
        #pragma unroll
        for (int r = 0; r < 4; ++r) {
          float s = a[rt][r] + xv[rt][r] + yv;
          rmin2[rt][r] = fminf(rmin2[rt][r], s);
          cm = fminf(cm, s);
        }
      }
      cm = fminf(cm, __shfl_xor(cm, 16, 64));
      cm = fminf(cm, __shfl_xor(cm, 32, 64));
      if (lane < 16) cminW[t & 1][wave * 64 + ct * 16 + lane] = cm;
    }
  }

  __syncthreads();  // final tile's cminW writes visible
  if (tid < 64) {
    float v = cminW[(TPB - 1) & 1][tid];
    #pragma unroll
    for (int w = 1; w < 8; ++w) v = fminf(v, cminW[(TPB - 1) & 1][w * 64 + tid]);
    colpart[(size_t)xg * (B_ * M_) + (size_t)b * M_ + (mc0 + (TPB - 1) * 64) + tid] = v;
  }

  // Row mins over this chunk: reduce across 16 col-lanes, store partial.
  #pragma unroll
  for (int rt = 0; rt < 4; ++rt) {
    #pragma unroll
    for (int r = 0; r < 4; ++r) {
      float v = rmin2[rt][r];
      v = fminf(v, __shfl_xor(v, 1, 64));
      v = fminf(v, __shfl_xor(v, 2, 64));
      v = fminf(v, __shfl_xor(v, 4, 64));
      v = fminf(v, __shfl_xor(v, 8, 64));
      if (l15 == 0)
        rowpart[(size_t)chunk * (B_ * N_) + (size_t)b * N_ + n0 + wave * 64 + rt * 16 + quad * 4 + r] = v;
    }
  }
}

// Pass 3: reduce partials (min over chunks/x-groups), sqrt, partial sums.
__global__ __launch_bounds__(256) void pass3_partial(
    const float* __restrict__ rowpart, const float* __restrict__ colpart,
    float* __restrict__ partial)
{
  const int BN = B_ * N_;
  float s1 = 0.0f, s2 = 0.0f;
  for (int i = blockIdx.x * 256 + threadIdx.x; i < BN; i += 64 * 256) {
    float r = rowpart[i];
    #pragma unroll
    for (int c = 1; c < CHUNKS; ++c) r = fminf(r, rowpart[c * BN + i]);
    s1 += sqrtf(fmaxf(r, 0.0f));
    float m = colpart[i];
    #pragma unroll
    for (int g = 1; g < XG; ++g) m = fminf(m, colpart[g * BN + i]);
    s2 += sqrtf(fmaxf(m, 0.0f));
  }
  #pragma unroll
  for (int m = 1; m < 64; m <<= 1) { s1 += __shfl_xor(s1, m, 64); s2 += __shfl_xor(s2, m, 64); }
  __shared__ float r1[4], r2[4];
  int wave = threadIdx.x >> 6, lane = threadIdx.x & 63;
  if (lane == 0) { r1[wave] = s1; r2[wave] = s2; }
  __syncthreads();
  if (threadIdx.x == 0) {
    partial[blockIdx.x]      = r1[0] + r1[1] + r1[2] + r1[3];
    partial[64 + blockIdx.x] = r2[0] + r2[1] + r2[2] + r2[3];
  }
}

// Pass 4: final 64->1 reduce, write scalar loss.
__global__ void pass4_final(const float* __restrict__ partial, float* __restrict__ out)
{
  int lane = threadIdx.x;
  float s = partial[lane] + partial[64 + lane];
  #pragma unroll
  for (int m = 1; m < 64; m <<= 1) s += __shfl_xor(s, m, 64);
  if (lane == 0) out[0] = s / (float)(B_ * N_);
}

extern "C" void kernel_launch(void* const* d_in, const int* in_sizes, int n_in,
                              void* d_out, int out_size, void* d_ws, size_t ws_size,
                              hipStream_t stream)
{
  const float* x = (const float*)d_in[0];
  const float* y = (const float*)d_in[1];
  char* ws = (char*)d_ws;

  unsigned short* xb = (unsigned short*)(ws);
  unsigned short* yb = (unsigned short*)(ws + (8u << 20));
  float* x2      = (float*)(ws + (16u << 20));
  float* y2      = (float*)(ws + (16u << 20) + (1u << 17));
  float* rowpart = (float*)(ws + (16u << 20) + (2u << 17));    // 8*B*N floats = 1 MB
  float* colpart = (float*)(ws + (16u << 20) + (10u << 17));   // 8*B*M floats = 1 MB
  float* partial = (float*)(ws + (16u << 20) + (18u << 17));
  float* outf = (float*)d_out;

  pass1_prep<<<(B_ * N_) / 4, 256, 0, stream>>>(x, y, xb, yb, x2, y2);

  pass2_tile<<<B_ * XG * CHUNKS, 512, 0, stream>>>(xb, yb, x2, y2, rowpart, colpart);

  pass3_partial<<<64, 256, 0, stream>>>(rowpart, colpart, partial);
  pass4_final<<<1, 64, 0, stream>>>(partial, outf);
}

// Round 11
// 121.620 us; speedup vs baseline: 1.0575x; 1.0575x over previous
//
#include <hip/hip_runtime.h>
#include <cstdint>

// Chamfer distance, B=8, N=M=4096, D=128, f32 in, scalar f32 out.
// R11: (1) remove amdgpu_waves_per_eu entirely — test whether the attr was
// capping HW occupancy at 1 block/CU (R9/R10 both pinned at 19% with it).
// (2) Kill in-loop serial stalls: no __shfl_xor in the ct-loop (each lane
// ds_writes its partial col-min; flush reduces 32 entries, overlapped).
// (3) acc init = x2 row values -> epilogue is 1 add + 2 fmin per element.
// (4) pass4 fused into pass3 (atomicAdd, d_out zeroed via hipMemsetAsync).
// Geometry: R10's 512 blocks x (512 rows x 512 cols), 64-col dbuf y-tiles,
// ~50 KB LDS.

#define B_   8
#define N_   4096
#define M_   4096
#define D_   128
#define TPB  8               // y-tiles (64 cols) per block -> 512 cols/chunk
#define ROWS_PB 512          // x-rows per block = 8 waves * 64
#define XG   (N_ / ROWS_PB)  // 8 x-groups
#define CHUNKS (M_ / (TPB * 64))   // 8 y-chunks

typedef __bf16 bf16x8 __attribute__((ext_vector_type(8)));
typedef float  f32x4  __attribute__((ext_vector_type(4)));
typedef unsigned int u32;

static __device__ __forceinline__ unsigned short f2bf(float f) {
  unsigned u = __float_as_uint(f);
  u += 0x7FFFu + ((u >> 16) & 1u);   // round-to-nearest-even
  return (unsigned short)(u >> 16);
}

static __device__ __forceinline__ void gld16(void* lds, const void* g) {
  __builtin_amdgcn_global_load_lds(
      (const __attribute__((address_space(1))) void*)g,
      (__attribute__((address_space(3))) void*)lds, 16, 0, 0);
}

// Pass 1: wave handles 2 rows (32 lanes x float4 each). xb = bf16(-2x),
// yb = bf16(y), fp32 norms.
__global__ __launch_bounds__(256) void pass1_prep(
    const float* __restrict__ x, const float* __restrict__ y,
    unsigned short* __restrict__ xb, unsigned short* __restrict__ yb,
    float* __restrict__ x2, float* __restrict__ y2)
{
  const int ROWS = B_ * N_;
  int gw   = (blockIdx.x * 256 + threadIdx.x) >> 6;   // wave id
  int lane = threadIdx.x & 63;
  int half = lane >> 5, sub = lane & 31;
  int row2 = gw * 2 + half;                  // 0 .. 2*ROWS-1 (x rows then y rows)
  bool isx = row2 < ROWS;
  const float* src; unsigned short* dst; float* nrm; int row;
  if (isx) { src = x; dst = xb; nrm = x2; row = row2; }
  else     { src = y; dst = yb; nrm = y2; row = row2 - ROWS; }
  size_t base = (size_t)row * D_ + sub * 4;
  float4 v = *(const float4*)(src + base);
  float sx = isx ? -2.0f : 1.0f;
  u32 p0 = (u32)f2bf(sx * v.x) | ((u32)f2bf(sx * v.y) << 16);
  u32 p1 = (u32)f2bf(sx * v.z) | ((u32)f2bf(sx * v.w) << 16);
  *(uint2*)(dst + base) = make_uint2(p0, p1);
  float s = v.x * v.x + v.y * v.y + v.z * v.z + v.w * v.w;
  #pragma unroll
  for (int m = 1; m < 32; m <<= 1) s += __shfl_xor(s, m, 64);
  if (sub == 0) nrm[row] = s;
}

// Pass 2: block = 512 x-rows (8 waves x 64 rows = 4 row-tiles of 16), loops
// over TPB y-tiles of 64 cols. y staged by global_load_lds into XOR-swizzled
// LDS (row r, logical 16B-chunk c at physical chunk c^(r&15); 256 B rows).
// Fragment layouts (HW-verified):
//   A/B operand: lane holds elems [row=lane&15][k=(lane>>4)*8 + 0..7]
//   C/D:         lane reg r holds [row=(lane>>4)*4+r][col=lane&15]
// acc init = x2_i, so final a = x2_i - 2<x,y>; s = a + y2_j = d^2.
// Col-min: per-lane partial -> ds_write (no cross-lane in hot loop);
// flush reduces the 32 (wave,quad) partials while next tile computes.
__global__ __launch_bounds__(512) void pass2_tile(
    const unsigned short* __restrict__ xb, const unsigned short* __restrict__ yb,
    const float* __restrict__ x2, const float* __restrict__ y2,
    float* __restrict__ rowpart, float* __restrict__ colpart)
{
  __shared__ unsigned short ys[2 * 8192];    // two 16 KB swizzled y-tiles (64 rows)
  __shared__ float cminW[2][32 * 64];        // dbuf per-(wave,quad) col-min partials (16 KB)
  __shared__ float y2s[TPB * 64];            // whole chunk's y^2 (2 KB)

  const int tid  = threadIdx.x;
  const int wave = tid >> 6;                 // 0..7
  const int lane = tid & 63;
  const int quad = lane >> 4;
  const int l15  = lane & 15;

  const int id    = blockIdx.x;        // 0..511
  const int b     = id & 7;
  const int j     = id >> 3;           // 0..63
  const int xg    = j & 7;
  const int chunk = j >> 3;            // 0..7
  const int n0    = xg * ROWS_PB;
  const int mc0   = chunk * (TPB * 64);

  // DMA: 16KB tile, 2 gld16 per lane: instr i covers bytes (wave*2+i)*1024+lane*16.
  int srcoff[2], ldsoff[2];
  #pragma unroll
  for (int i = 0; i < 2; ++i) {
    int p  = (wave * 2 + i) * 1024 + lane * 16;
    int r  = p >> 8;                 // y row 0..63
    int pc = (p >> 4) & 15;          // physical chunk
    int c  = pc ^ (r & 15);          // logical chunk
    srcoff[i] = r * D_ + c * 8;      // elements
    ldsoff[i] = (wave * 2 + i) * 1024;
  }

  // preload tile 0 + whole-chunk y2 into LDS
  {
    const unsigned short* src = yb + ((size_t)b * M_ + mc0) * D_;
    gld16((char*)ys + ldsoff[0], src + srcoff[0]);
    gld16((char*)ys + ldsoff[1], src + srcoff[1]);
  }
  if (tid < TPB * 64) y2s[tid] = y2[(size_t)b * M_ + mc0 + tid];

  // A fragments: direct global->register, rows n0 + wave*64 + rt*16 + l15.
  bf16x8 afrag[4][4];   // [kb][rt]
  const size_t xrow0 = (size_t)b * N_ + n0 + wave * 64;
  #pragma unroll
  for (int kb = 0; kb < 4; ++kb)
    #pragma unroll
    for (int rt = 0; rt < 4; ++rt)
      afrag[kb][rt] = *(const bf16x8*)(xb + (xrow0 + rt * 16 + l15) * D_ + kb * 32 + quad * 8);

  // x2 for this wave's 16 output rows (t-invariant), kept as f32x4 for acc init
  f32x4 xvv[4];
  #pragma unroll
  for (int rt = 0; rt < 4; ++rt)
    #pragma unroll
    for (int r = 0; r < 4; ++r)
      xvv[rt][r] = x2[(size_t)b * N_ + n0 + wave * 64 + rt * 16 + quad * 4 + r];

  const float FINF = __uint_as_float(0x7F800000u);
  float rmin2[4][4];
  #pragma unroll
  for (int rt = 0; rt < 4; ++rt)
    #pragma unroll
    for (int r = 0; r < 4; ++r) rmin2[rt][r] = FINF;

  #pragma unroll 1
  for (int t = 0; t < TPB; ++t) {
    const int m0 = mc0 + t * 64;
    const int d  = (t & 1) * 16384;    // current buffer byte offset
    __syncthreads();  // drains DMA for buf d (prefetch had a full iteration);
                      // fences prior buf reads and cminW[(t-1)&1] writes

    if (t + 1 < TPB) {  // prefetch next tile into the other buffer
      const unsigned short* src = yb + ((size_t)b * M_ + m0 + 64) * D_;
      char* dst = (char*)ys + (16384 - d);
      gld16(dst + ldsoff[0], src + srcoff[0]);
      gld16(dst + ldsoff[1], src + srcoff[1]);
    }

    // Flush previous tile's column mins (other cminW buffer -> no race):
    // col j's min = min over 32 (wave,quad) partials.
    if (t > 0 && tid < 64) {
      const float* cb = cminW[(t - 1) & 1];
      float v = cb[tid];
      #pragma unroll
      for (int w = 1; w < 32; ++w) v = fminf(v, cb[w * 64 + tid]);
      colpart[(size_t)xg * (B_ * M_) + (size_t)b * M_ + (m0 - 64) + tid] = v;
    }

    #pragma unroll
    for (int ct = 0; ct < 4; ++ct) {
      f32x4 a[4];
      #pragma unroll
      for (int rt = 0; rt < 4; ++rt) a[rt] = xvv[rt];   // acc init = x2
      #pragma unroll
      for (int kb = 0; kb < 4; ++kb) {
        const int row = ct * 16 + l15;
        const int pcB = (kb * 4 + quad) ^ l15;   // swizzled chunk
        bf16x8 bfr = *(const bf16x8*)((const char*)ys + d + row * 256 + pcB * 16);
        #pragma unroll
        for (int rt = 0; rt < 4; ++rt)
          a[rt] = __builtin_amdgcn_mfma_f32_16x16x32_bf16(afrag[kb][rt], bfr, a[rt], 0, 0, 0);
      }
      float yv = y2s[t * 64 + ct * 16 + l15];  // quads share addr -> broadcast
      float cm = FINF;
      #pragma unroll
      for (int rt = 0; rt < 4; ++rt) {
        #pragma unroll
        for (int r = 0; r < 4; ++r) {
          float s = a[rt][r] + yv;             // = x2_i + y2_j - 2<x,y>
          rmin2[rt][r] = fminf(rmin2[rt][r], s);
          cm = fminf(cm, s);
        }
      }
      // per-lane partial col-min straight to LDS (no cross-lane, no wait)
      cminW[t & 1][(wave * 4 + quad) * 64 + ct * 16 + l15] = cm;
    }
  }

  __syncthreads();  // final tile's cminW writes visible
  if (tid < 64) {
    const float* cb = cminW[(TPB - 1) & 1];
    float v = cb[tid];
    #pragma unroll
    for (int w = 1; w < 32; ++w) v = fminf(v, cb[w * 64 + tid]);
    colpart[(size_t)xg * (B_ * M_) + (size_t)b * M_ + (mc0 + (TPB - 1) * 64) + tid] = v;
  }

  // Row mins over this chunk: reduce across 16 col-lanes (once, at the end).
  #pragma unroll
  for (int rt = 0; rt < 4; ++rt) {
    #pragma unroll
    for (int r = 0; r < 4; ++r) {
      float v = rmin2[rt][r];
      v = fminf(v, __shfl_xor(v, 1, 64));
      v = fminf(v, __shfl_xor(v, 2, 64));
      v = fminf(v, __shfl_xor(v, 4, 64));
      v = fminf(v, __shfl_xor(v, 8, 64));
      if (l15 == 0)
        rowpart[(size_t)chunk * (B_ * N_) + (size_t)b * N_ + n0 + wave * 64 + rt * 16 + quad * 4 + r] = v;
    }
  }
}

// Pass 3: reduce partials (min over chunks/x-groups), sqrt, sum, atomicAdd
// the block's contribution to the final scalar (d_out pre-zeroed).
__global__ __launch_bounds__(256) void pass3_final(
    const float* __restrict__ rowpart, const float* __restrict__ colpart,
    float* __restrict__ out)
{
  const int BN = B_ * N_;
  float s1 = 0.0f, s2 = 0.0f;
  for (int i = blockIdx.x * 256 + threadIdx.x; i < BN; i += 64 * 256) {
    float r = rowpart[i];
    #pragma unroll
    for (int c = 1; c < CHUNKS; ++c) r = fminf(r, rowpart[c * BN + i]);
    s1 += sqrtf(fmaxf(r, 0.0f));
    float m = colpart[i];
    #pragma unroll
    for (int g = 1; g < XG; ++g) m = fminf(m, colpart[g * BN + i]);
    s2 += sqrtf(fmaxf(m, 0.0f));
  }
  float s = s1 + s2;
  #pragma unroll
  for (int m = 1; m < 64; m <<= 1) s += __shfl_xor(s, m, 64);
  __shared__ float r1[4];
  int wave = threadIdx.x >> 6, lane = threadIdx.x & 63;
  if (lane == 0) r1[wave] = s;
  __syncthreads();
  if (threadIdx.x == 0)
    atomicAdd(out, (r1[0] + r1[1] + r1[2] + r1[3]) / (float)(B_ * N_));
}

extern "C" void kernel_launch(void* const* d_in, const int* in_sizes, int n_in,
                              void* d_out, int out_size, void* d_ws, size_t ws_size,
                              hipStream_t stream)
{
  const float* x = (const float*)d_in[0];
  const float* y = (const float*)d_in[1];
  char* ws = (char*)d_ws;

  unsigned short* xb = (unsigned short*)(ws);
  unsigned short* yb = (unsigned short*)(ws + (8u << 20));
  float* x2      = (float*)(ws + (16u << 20));
  float* y2      = (float*)(ws + (16u << 20) + (1u << 17));
  float* rowpart = (float*)(ws + (16u << 20) + (2u << 17));    // 8*B*N floats = 1 MB
  float* colpart = (float*)(ws + (16u << 20) + (10u << 17));   // 8*B*M floats = 1 MB
  float* outf = (float*)d_out;

  hipMemsetAsync(outf, 0, sizeof(float), stream);  // atomicAdd target

  pass1_prep<<<(B_ * N_) / 4, 256, 0, stream>>>(x, y, xb, yb, x2, y2);

  pass2_tile<<<B_ * XG * CHUNKS, 512, 0, stream>>>(xb, yb, x2, y2, rowpart, colpart);

  pass3_final<<<64, 256, 0, stream>>>(rowpart, colpart, outf);
}

// Round 12
// 121.245 us; speedup vs baseline: 1.0608x; 1.0031x over previous
//
#include <hip/hip_runtime.h>
#include <cstdint>

// Chamfer distance, B=8, N=M=4096, D=128, f32 in, scalar f32 out.
// R12: back to the ONLY geometry that demonstrably co-resides >1 block/CU on
// this stack: 256-thread blocks (R2-R4 hit ~40% occupancy = 3+ blocks/CU).
// 4 waves x 64 rows (rt=4), 64-col DMA-staged dbuf y-tiles, ~40KB LDS ->
// 3-4 blocks/CU = 3-4 waves/SIMD (R8-R11 were stuck at 2/SIMD = latency
// starved: all pipes <30% busy). VGPR ~130 via single-arg LB(256) (R1
// precedent, no 64-cap, no spill).
// Workspace: xb(8M) yb(8M) x2(128K) y2(128K) rowpart(1M) colpart(2M).

#define B_   8
#define N_   4096
#define M_   4096
#define D_   128
#define TPB  8               // y-tiles (64 cols) per block -> 512-col chunk
#define ROWS_PB 256          // x-rows per block = 4 waves * 64
#define XG   (N_ / ROWS_PB)  // 16 x-groups
#define CHUNKS (M_ / (TPB * 64))   // 8 y-chunks

typedef __bf16 bf16x8 __attribute__((ext_vector_type(8)));
typedef float  f32x4  __attribute__((ext_vector_type(4)));
typedef unsigned int u32;

static __device__ __forceinline__ unsigned short f2bf(float f) {
  unsigned u = __float_as_uint(f);
  u += 0x7FFFu + ((u >> 16) & 1u);   // round-to-nearest-even
  return (unsigned short)(u >> 16);
}

static __device__ __forceinline__ void gld16(void* lds, const void* g) {
  __builtin_amdgcn_global_load_lds(
      (const __attribute__((address_space(1))) void*)g,
      (__attribute__((address_space(3))) void*)lds, 16, 0, 0);
}

// Pass 1: wave handles 2 rows (32 lanes x float4 each). xb = bf16(-2x),
// yb = bf16(y), fp32 norms.
__global__ __launch_bounds__(256) void pass1_prep(
    const float* __restrict__ x, const float* __restrict__ y,
    unsigned short* __restrict__ xb, unsigned short* __restrict__ yb,
    float* __restrict__ x2, float* __restrict__ y2)
{
  const int ROWS = B_ * N_;
  int gw   = (blockIdx.x * 256 + threadIdx.x) >> 6;   // wave id
  int lane = threadIdx.x & 63;
  int half = lane >> 5, sub = lane & 31;
  int row2 = gw * 2 + half;                  // 0 .. 2*ROWS-1 (x rows then y rows)
  bool isx = row2 < ROWS;
  const float* src; unsigned short* dst; float* nrm; int row;
  if (isx) { src = x; dst = xb; nrm = x2; row = row2; }
  else     { src = y; dst = yb; nrm = y2; row = row2 - ROWS; }
  size_t base = (size_t)row * D_ + sub * 4;
  float4 v = *(const float4*)(src + base);
  float sx = isx ? -2.0f : 1.0f;
  u32 p0 = (u32)f2bf(sx * v.x) | ((u32)f2bf(sx * v.y) << 16);
  u32 p1 = (u32)f2bf(sx * v.z) | ((u32)f2bf(sx * v.w) << 16);
  *(uint2*)(dst + base) = make_uint2(p0, p1);
  float s = v.x * v.x + v.y * v.y + v.z * v.z + v.w * v.w;
  #pragma unroll
  for (int m = 1; m < 32; m <<= 1) s += __shfl_xor(s, m, 64);
  if (sub == 0) nrm[row] = s;
}

// Pass 2: block = 256 x-rows (4 waves x 64 rows = 4 row-tiles of 16), loops
// over TPB y-tiles of 64 cols. y staged by global_load_lds into XOR-swizzled
// LDS (row r, logical 16B-chunk c at physical chunk c^(r&15); 256 B rows).
// Fragment layouts (HW-verified):
//   A/B operand: lane holds elems [row=lane&15][k=(lane>>4)*8 + 0..7]
//   C/D:         lane reg r holds [row=(lane>>4)*4+r][col=lane&15]
// acc init = x2_i, so final a = x2_i - 2<x,y>; s = a + y2_j = d^2.
__global__ __launch_bounds__(256) void pass2_tile(
    const unsigned short* __restrict__ xb, const unsigned short* __restrict__ yb,
    const float* __restrict__ x2, const float* __restrict__ y2,
    float* __restrict__ rowpart, float* __restrict__ colpart)
{
  __shared__ unsigned short ys[2 * 8192];    // two 16 KB swizzled y-tiles (64 rows)
  __shared__ float cminW[2][16 * 64];        // dbuf per-(wave,quad) col-min partials (8 KB)

  const int tid  = threadIdx.x;
  const int wave = tid >> 6;                 // 0..3
  const int lane = tid & 63;
  const int quad = lane >> 4;
  const int l15  = lane & 15;

  const int id    = blockIdx.x;        // 0..1023
  const int b     = id & 7;
  const int xg    = (id >> 3) & 15;
  const int chunk = id >> 7;           // 0..7
  const int n0    = xg * ROWS_PB;
  const int mc0   = chunk * (TPB * 64);

  // DMA: 16KB tile, 4 gld16 per lane: instr i covers bytes (wave*4+i)*1024+lane*16.
  int srcoff[4], ldsoff[4];
  #pragma unroll
  for (int i = 0; i < 4; ++i) {
    int p  = (wave * 4 + i) * 1024 + lane * 16;
    int r  = p >> 8;                 // y row 0..63
    int pc = (p >> 4) & 15;          // physical chunk
    int c  = pc ^ (r & 15);          // logical chunk
    srcoff[i] = r * D_ + c * 8;      // elements
    ldsoff[i] = (wave * 4 + i) * 1024;
  }

  // preload tile 0
  {
    const unsigned short* src = yb + ((size_t)b * M_ + mc0) * D_;
    #pragma unroll
    for (int i = 0; i < 4; ++i) gld16((char*)ys + ldsoff[i], src + srcoff[i]);
  }

  // A fragments: direct global->register, rows n0 + wave*64 + rt*16 + l15.
  bf16x8 afrag[4][4];   // [kb][rt]
  const size_t xrow0 = (size_t)b * N_ + n0 + wave * 64;
  #pragma unroll
  for (int kb = 0; kb < 4; ++kb)
    #pragma unroll
    for (int rt = 0; rt < 4; ++rt)
      afrag[kb][rt] = *(const bf16x8*)(xb + (xrow0 + rt * 16 + l15) * D_ + kb * 32 + quad * 8);

  // x2 for this wave's 16 output rows (t-invariant), as f32x4 for acc init
  f32x4 xvv[4];
  #pragma unroll
  for (int rt = 0; rt < 4; ++rt)
    #pragma unroll
    for (int r = 0; r < 4; ++r)
      xvv[rt][r] = x2[(size_t)b * N_ + n0 + wave * 64 + rt * 16 + quad * 4 + r];

  const float FINF = __uint_as_float(0x7F800000u);
  float rmin2[4][4];
  #pragma unroll
  for (int rt = 0; rt < 4; ++rt)
    #pragma unroll
    for (int r = 0; r < 4; ++r) rmin2[rt][r] = FINF;

  #pragma unroll 1
  for (int t = 0; t < TPB; ++t) {
    const int m0 = mc0 + t * 64;
    const int d  = (t & 1) * 16384;    // current buffer byte offset
    __syncthreads();  // drains DMA for buf d (prefetch had a full iteration);
                      // fences prior buf reads and cminW[(t-1)&1] writes

    // per-tile y^2: 4 per-lane scalars (16-lane coalesced, quad-broadcast)
    float y2r[4];
    #pragma unroll
    for (int ct = 0; ct < 4; ++ct)
      y2r[ct] = y2[(size_t)b * M_ + m0 + ct * 16 + l15];

    if (t + 1 < TPB) {  // prefetch next tile into the other buffer
      const unsigned short* src = yb + ((size_t)b * M_ + m0 + 64) * D_;
      char* dst = (char*)ys + (16384 - d);
      #pragma unroll
      for (int i = 0; i < 4; ++i) gld16(dst + ldsoff[i], src + srcoff[i]);
    }

    // Flush previous tile's column mins (other cminW buffer -> no race):
    // col j's min = min over 16 (wave,quad) partials.
    if (t > 0 && tid < 64) {
      const float* cb = cminW[(t - 1) & 1];
      float v = cb[tid];
      #pragma unroll
      for (int w = 1; w < 16; ++w) v = fminf(v, cb[w * 64 + tid]);
      colpart[(size_t)xg * (B_ * M_) + (size_t)b * M_ + (m0 - 64) + tid] = v;
    }

    #pragma unroll
    for (int ct = 0; ct < 4; ++ct) {
      f32x4 a[4];
      #pragma unroll
      for (int rt = 0; rt < 4; ++rt) a[rt] = xvv[rt];   // acc init = x2
      #pragma unroll
      for (int kb = 0; kb < 4; ++kb) {
        const int row = ct * 16 + l15;
        const int pcB = (kb * 4 + quad) ^ l15;   // swizzled chunk
        bf16x8 bfr = *(const bf16x8*)((const char*)ys + d + row * 256 + pcB * 16);
        #pragma unroll
        for (int rt = 0; rt < 4; ++rt)
          a[rt] = __builtin_amdgcn_mfma_f32_16x16x32_bf16(afrag[kb][rt], bfr, a[rt], 0, 0, 0);
      }
      float yv = y2r[ct];
      float cm = FINF;
      #pragma unroll
      for (int rt = 0; rt < 4; ++rt) {
        #pragma unroll
        for (int r = 0; r < 4; ++r) {
          float s = a[rt][r] + yv;             // = x2_i + y2_j - 2<x,y>
          rmin2[rt][r] = fminf(rmin2[rt][r], s);
          cm = fminf(cm, s);
        }
      }
      // per-lane partial col-min straight to LDS (no cross-lane, no wait)
      cminW[t & 1][(wave * 4 + quad) * 64 + ct * 16 + l15] = cm;
    }
  }

  __syncthreads();  // final tile's cminW writes visible
  if (tid < 64) {
    const float* cb = cminW[(TPB - 1) & 1];
    float v = cb[tid];
    #pragma unroll
    for (int w = 1; w < 16; ++w) v = fminf(v, cb[w * 64 + tid]);
    colpart[(size_t)xg * (B_ * M_) + (size_t)b * M_ + (mc0 + (TPB - 1) * 64) + tid] = v;
  }

  // Row mins over this chunk: reduce across 16 col-lanes (once, at the end).
  #pragma unroll
  for (int rt = 0; rt < 4; ++rt) {
    #pragma unroll
    for (int r = 0; r < 4; ++r) {
      float v = rmin2[rt][r];
      v = fminf(v, __shfl_xor(v, 1, 64));
      v = fminf(v, __shfl_xor(v, 2, 64));
      v = fminf(v, __shfl_xor(v, 4, 64));
      v = fminf(v, __shfl_xor(v, 8, 64));
      if (l15 == 0)
        rowpart[(size_t)chunk * (B_ * N_) + (size_t)b * N_ + n0 + wave * 64 + rt * 16 + quad * 4 + r] = v;
    }
  }
}

// Pass 3: reduce partials (min over chunks/x-groups), sqrt, sum, atomicAdd
// the block's contribution to the final scalar (d_out pre-zeroed).
__global__ __launch_bounds__(256) void pass3_final(
    const float* __restrict__ rowpart, const float* __restrict__ colpart,
    float* __restrict__ out)
{
  const int BN = B_ * N_;
  float s1 = 0.0f, s2 = 0.0f;
  for (int i = blockIdx.x * 256 + threadIdx.x; i < BN; i += 64 * 256) {
    float r = rowpart[i];
    #pragma unroll
    for (int c = 1; c < CHUNKS; ++c) r = fminf(r, rowpart[c * BN + i]);
    s1 += sqrtf(fmaxf(r, 0.0f));
    float m = colpart[i];
    #pragma unroll
    for (int g = 1; g < XG; ++g) m = fminf(m, colpart[g * BN + i]);
    s2 += sqrtf(fmaxf(m, 0.0f));
  }
  float s = s1 + s2;
  #pragma unroll
  for (int m = 1; m < 64; m <<= 1) s += __shfl_xor(s, m, 64);
  __shared__ float r1[4];
  int wave = threadIdx.x >> 6, lane = threadIdx.x & 63;
  if (lane == 0) r1[wave] = s;
  __syncthreads();
  if (threadIdx.x == 0)
    atomicAdd(out, (r1[0] + r1[1] + r1[2] + r1[3]) / (float)(B_ * N_));
}

extern "C" void kernel_launch(void* const* d_in, const int* in_sizes, int n_in,
                              void* d_out, int out_size, void* d_ws, size_t ws_size,
                              hipStream_t stream)
{
  const float* x = (const float*)d_in[0];
  const float* y = (const float*)d_in[1];
  char* ws = (char*)d_ws;

  unsigned short* xb = (unsigned short*)(ws);
  unsigned short* yb = (unsigned short*)(ws + (8u << 20));
  float* x2      = (float*)(ws + (16u << 20));
  float* y2      = (float*)(ws + (16u << 20) + (1u << 17));
  float* rowpart = (float*)(ws + (16u << 20) + (2u << 17));    // 8*B*N floats = 1 MB
  float* colpart = (float*)(ws + (16u << 20) + (10u << 17));   // 16*B*M floats = 2 MB
  float* outf = (float*)d_out;

  hipMemsetAsync(outf, 0, sizeof(float), stream);  // atomicAdd target

  pass1_prep<<<(B_ * N_) / 4, 256, 0, stream>>>(x, y, xb, yb, x2, y2);

  pass2_tile<<<B_ * XG * CHUNKS, 256, 0, stream>>>(xb, yb, x2, y2, rowpart, colpart);

  pass3_final<<<64, 256, 0, stream>>>(rowpart, colpart, outf);
}